// Round 1
// baseline (223.288 us; speedup 1.0000x reference)
//
#include <hip/hip_runtime.h>

constexpr int N_VARS   = 2048;
constexpr int N_LAYERS = 8;
constexpr int NODES    = 4096;
constexpr int BATCH    = 8192;
constexpr int THREADS  = 256;
constexpr int RPB      = 2;                 // batch rows per block (float2 lanes)
constexpr int NPT      = NODES / THREADS;   // 16 nodes per thread per layer

// One layer: gather 4 children from src (LDS), prod or sum, write dst (LDS).
// I64: child_idx stored as int64 words (values < 4096 -> low word only).
template <bool PROD, bool I64>
__device__ __forceinline__ void layer_pass(const float2* __restrict__ src,
                                           float2* __restrict__ dst,
                                           const int* __restrict__ idxbase,
                                           int t)
{
#pragma unroll
  for (int i = 0; i < NPT; ++i) {
    const int n = t + i * THREADS;
    int4 c;
    if (!I64) {
      c = ((const int4*)idxbase)[n];
    } else {
      const int* p = idxbase + (size_t)n * 8;
      c.x = p[0]; c.y = p[2]; c.z = p[4]; c.w = p[6];
    }
    float2 a = src[c.x];
    float2 b = src[c.y];
    float2 e = src[c.z];
    float2 d = src[c.w];
    float2 v;
    if (PROD) {
      v.x = a.x * b.x * e.x * d.x;
      v.y = a.y * b.y * e.y * d.y;
    } else {
      v.x = a.x + b.x + e.x + d.x;
      v.y = a.y + b.y + e.y + d.y;
    }
    dst[n] = v;
  }
}

template <bool I64>
__device__ __forceinline__ void run_layers(float2 (*buf)[NODES],
                                           const int* __restrict__ cidx,
                                           int t)
{
  const int lstride = NODES * 4 * (I64 ? 2 : 1);  // int32 words per layer
  for (int l = 0; l < N_LAYERS; l += 2) {
    __syncthreads();
    layer_pass<true,  I64>(buf[0], buf[1], cidx + (size_t)l * lstride, t);
    __syncthreads();
    layer_pass<false, I64>(buf[1], buf[0], cidx + (size_t)(l + 1) * lstride, t);
  }
}

__global__ __launch_bounds__(THREADS) void spn_kernel(
    const float* __restrict__ x,
    const unsigned char* __restrict__ marg,
    const int* __restrict__ cidx,
    float* __restrict__ out)
{
  __shared__ float2 buf[2][NODES];  // 64 KB: [pingpong][node] -> (row0,row1)
  const int t = threadIdx.x;
  const int row0 = blockIdx.x * RPB;

  // Detect index storage width (wave-uniform: all threads read same words).
  // int64 storage => every odd int32 word is 0 (indices < 4096, positive).
  int acc = 0;
#pragma unroll
  for (int k = 0; k < 8; ++k) acc |= cidx[2 * k + 1];
  const bool i64 = (acc == 0);

  // Stage leaves: buf[0][j] = x[row][j], buf[0][2048+j] = 1-x[row][j]
  // (marginalized vars forced to 1.0 in both halves).
  const float4* x0 = (const float4*)(x + (size_t)row0 * N_VARS);
  const float4* x1 = (const float4*)(x + (size_t)(row0 + 1) * N_VARS);
  const uchar4* m4 = (const uchar4*)marg;
#pragma unroll
  for (int i = 0; i < N_VARS / 4 / THREADS; ++i) {  // 2 iterations
    const int j4 = t + i * THREADS;
    float4 a = x0[j4];
    float4 b = x1[j4];
    uchar4 m = m4[j4];
    float4 ia = make_float4(1.f - a.x, 1.f - a.y, 1.f - a.z, 1.f - a.w);
    float4 ib = make_float4(1.f - b.x, 1.f - b.y, 1.f - b.z, 1.f - b.w);
    if (m.x) { a.x = 1.f; b.x = 1.f; ia.x = 1.f; ib.x = 1.f; }
    if (m.y) { a.y = 1.f; b.y = 1.f; ia.y = 1.f; ib.y = 1.f; }
    if (m.z) { a.z = 1.f; b.z = 1.f; ia.z = 1.f; ib.z = 1.f; }
    if (m.w) { a.w = 1.f; b.w = 1.f; ia.w = 1.f; ib.w = 1.f; }
    const int j = 4 * j4;
    buf[0][j + 0] = make_float2(a.x, b.x);
    buf[0][j + 1] = make_float2(a.y, b.y);
    buf[0][j + 2] = make_float2(a.z, b.z);
    buf[0][j + 3] = make_float2(a.w, b.w);
    buf[0][N_VARS + j + 0] = make_float2(ia.x, ib.x);
    buf[0][N_VARS + j + 1] = make_float2(ia.y, ib.y);
    buf[0][N_VARS + j + 2] = make_float2(ia.z, ib.z);
    buf[0][N_VARS + j + 3] = make_float2(ia.w, ib.w);
  }

  if (i64) run_layers<true>(buf, cidx, t);
  else     run_layers<false>(buf, cidx, t);

  // Final reduction over nodes: result of layer 7 is in buf[0].
  __syncthreads();
  float2 s = make_float2(0.f, 0.f);
#pragma unroll
  for (int i = 0; i < NPT; ++i) {
    float2 v = buf[0][t + i * THREADS];
    s.x += v.x;
    s.y += v.y;
  }
#pragma unroll
  for (int off = 32; off > 0; off >>= 1) {
    s.x += __shfl_down(s.x, off);
    s.y += __shfl_down(s.y, off);
  }
  __syncthreads();                       // buf[1] now reusable as scratch
  if ((t & 63) == 0) buf[1][t >> 6] = s; // one partial per wave (4 waves)
  __syncthreads();
  if (t == 0) {
    float2 tot = make_float2(0.f, 0.f);
#pragma unroll
    for (int w = 0; w < THREADS / 64; ++w) {
      tot.x += buf[1][w].x;
      tot.y += buf[1][w].y;
    }
    out[row0]     = tot.x;
    out[row0 + 1] = tot.y;
  }
}

extern "C" void kernel_launch(void* const* d_in, const int* in_sizes, int n_in,
                              void* d_out, int out_size, void* d_ws, size_t ws_size,
                              hipStream_t stream) {
  const float* x          = (const float*)d_in[0];
  const unsigned char* mg = (const unsigned char*)d_in[1];
  const int* cidx         = (const int*)d_in[2];
  float* out              = (float*)d_out;

  dim3 grid(BATCH / RPB);   // 4096 blocks, 2 rows each
  dim3 block(THREADS);
  hipLaunchKernelGGL(spn_kernel, grid, block, 0, stream, x, mg, cidx, out);
}

// Round 3
// 201.985 us; speedup vs baseline: 1.1055x; 1.1055x over previous
//
#include <hip/hip_runtime.h>

constexpr int N_VARS   = 2048;
constexpr int NODES    = 4096;
constexpr int N_LAYERS = 8;
constexpr int BATCH    = 8192;
constexpr int THREADS  = 256;
constexpr int RPB      = 2;                 // batch rows per block
constexpr int NPT      = NODES / THREADS;   // 16 nodes/thread/layer

// ---- bf16x2 word = row0 bf16 (low 16) | row1 bf16 (high 16) ----
__device__ __forceinline__ float bflo(unsigned w) { return __uint_as_float(w << 16); }
__device__ __forceinline__ float bfhi(unsigned w) { return __uint_as_float(w & 0xffff0000u); }
__device__ __forceinline__ unsigned bfpack(float a, float b) {   // RNE both
  unsigned ua = __float_as_uint(a), ub = __float_as_uint(b);
  ua = (ua + 0x7fffu + ((ua >> 16) & 1u)) >> 16;
  ub = (ub + 0x7fffu + ((ub >> 16) & 1u)) & 0xffff0000u;
  return ua | ub;
}

// MODE: 0 = pre-packed ushort4 (d_ws), 1 = raw int32, 2 = raw int64 words
template <int MODE>
__device__ __forceinline__ ushort4 get_idx(const void* p, int n) {
  if (MODE == 0) return ((const ushort4*)p)[n];
  if (MODE == 1) {
    int4 c = ((const int4*)p)[n];
    return make_ushort4((unsigned short)c.x, (unsigned short)c.y,
                        (unsigned short)c.z, (unsigned short)c.w);
  }
  const int* q = (const int*)p + (size_t)n * 8;
  return make_ushort4((unsigned short)q[0], (unsigned short)q[2],
                      (unsigned short)q[4], (unsigned short)q[6]);
}
template <int MODE> __device__ __forceinline__ size_t layer_bytes() {
  return MODE == 0 ? (size_t)NODES * 8 : MODE == 1 ? (size_t)NODES * 16
                                                   : (size_t)NODES * 32;
}

// Prod layer: gather fp32 float2 from A, multiply in fp32, store bf16x2 to B.
// (Rounding here feeds a SUM layer -> attenuated by averaging.)
template <int MODE>
__device__ __forceinline__ void prod_pass(const float2* A, unsigned* B,
                                          const void* idx, int t) {
#pragma unroll
  for (int i = 0; i < NPT; ++i) {
    const int n = t + i * THREADS;
    ushort4 c = get_idx<MODE>(idx, n);
    float2 a = A[c.x], b = A[c.y], d = A[c.z], e = A[c.w];
    B[n] = bfpack(a.x * b.x * d.x * e.x, a.y * b.y * d.y * e.y);
  }
}

// Sum layer: gather bf16x2 from B, add in fp32, store fp32 float2 to A.
// (Output feeds a PROD layer -> stored exactly, no rounding.)
template <int MODE>
__device__ __forceinline__ void sum_pass(const unsigned* B, float2* A,
                                         const void* idx, int t) {
#pragma unroll
  for (int i = 0; i < NPT; ++i) {
    const int n = t + i * THREADS;
    ushort4 c = get_idx<MODE>(idx, n);
    unsigned a = B[c.x], b = B[c.y], d = B[c.z], e = B[c.w];
    A[n] = make_float2(bflo(a) + bflo(b) + bflo(d) + bflo(e),
                       bfhi(a) + bfhi(b) + bfhi(d) + bfhi(e));
  }
}

template <int MODE>
__device__ __forceinline__ void spn_body(const float* __restrict__ x,
                                         const unsigned char* __restrict__ marg,
                                         const void* __restrict__ idx,
                                         float* __restrict__ out,
                                         float2* A,          // 4096 fp32x2 = 32 KB
                                         unsigned* B) {      // 4096 bf16x2 = 16 KB
  const int t = threadIdx.x;
  const int row0 = blockIdx.x * RPB;
  const float* x0 = x + (size_t)row0 * N_VARS;
  const float* x1 = x0 + N_VARS;

  // Stage leaves in fp32 (leaf rounding would be prod-amplified -> keep exact).
#pragma unroll
  for (int i = 0; i < N_VARS / THREADS; ++i) {  // 8 iterations
    const int j = t + i * THREADS;
    const float a = x0[j], b = x1[j];
    const bool m = marg[j] != 0;
    A[j]          = make_float2(m ? 1.f : a,       m ? 1.f : b);
    A[N_VARS + j] = make_float2(m ? 1.f : 1.f - a, m ? 1.f : 1.f - b);
  }

  const char* ib = (const char*)idx;
  const size_t LB = layer_bytes<MODE>();
  __syncthreads();
  prod_pass<MODE>(A, B, ib + 0 * LB, t); __syncthreads();   // L0
  sum_pass <MODE>(B, A, ib + 1 * LB, t); __syncthreads();   // L1 (overwrites leaves)
  prod_pass<MODE>(A, B, ib + 2 * LB, t); __syncthreads();   // L2
  sum_pass <MODE>(B, A, ib + 3 * LB, t); __syncthreads();   // L3
  prod_pass<MODE>(A, B, ib + 4 * LB, t); __syncthreads();   // L4
  sum_pass <MODE>(B, A, ib + 5 * LB, t); __syncthreads();   // L5
  prod_pass<MODE>(A, B, ib + 6 * LB, t); __syncthreads();   // L6

  // L7 (sum) fused into node reduction: gather bf16 from B, accumulate fp32.
  float s0 = 0.f, s1 = 0.f;
  {
    const void* L7 = ib + 7 * LB;
#pragma unroll
    for (int i = 0; i < NPT; ++i) {
      const int n = t + i * THREADS;
      ushort4 c = get_idx<MODE>(L7, n);
      unsigned a = B[c.x], b = B[c.y], d = B[c.z], e = B[c.w];
      s0 += bflo(a) + bflo(b) + bflo(d) + bflo(e);
      s1 += bfhi(a) + bfhi(b) + bfhi(d) + bfhi(e);
    }
  }
#pragma unroll
  for (int off = 32; off > 0; off >>= 1) {
    s0 += __shfl_down(s0, off);
    s1 += __shfl_down(s1, off);
  }
  if ((t & 63) == 0) A[t >> 6] = make_float2(s0, s1);  // A free after last sync
  __syncthreads();
  if (t == 0) {
    float2 tot = A[0];
#pragma unroll
    for (int w = 1; w < THREADS / 64; ++w) { tot.x += A[w].x; tot.y += A[w].y; }
    out[row0]     = tot.x;
    out[row0 + 1] = tot.y;
  }
}

__global__ __launch_bounds__(THREADS) void spn_packed(
    const float* __restrict__ x, const unsigned char* __restrict__ marg,
    const ushort4* __restrict__ idx, float* __restrict__ out) {
  __shared__ float2   A[NODES];   // 32 KB
  __shared__ unsigned B[NODES];   // 16 KB  -> 48 KB total, 3 blocks/CU
  spn_body<0>(x, marg, idx, out, A, B);
}

__global__ __launch_bounds__(THREADS) void spn_raw(
    const float* __restrict__ x, const unsigned char* __restrict__ marg,
    const int* __restrict__ cidx, float* __restrict__ out) {
  __shared__ float2   A[NODES];
  __shared__ unsigned B[NODES];
  int acc = 0;  // int64 storage => odd words all zero (indices < 4096)
#pragma unroll
  for (int k = 0; k < 8; ++k) acc |= cidx[2 * k + 1];
  if (acc == 0) spn_body<2>(x, marg, cidx, out, A, B);
  else          spn_body<1>(x, marg, cidx, out, A, B);
}

// One-time (per launch) index pack: int64/int32 -> ushort4 per node.
__global__ void pack_idx(const int* __restrict__ cidx, ushort4* __restrict__ out) {
  const int g = blockIdx.x * blockDim.x + threadIdx.x;  // 0 .. N_LAYERS*NODES-1
  int acc = 0;
#pragma unroll
  for (int k = 0; k < 8; ++k) acc |= cidx[2 * k + 1];
  ushort4 r;
  if (acc == 0) {
    const int* p = cidx + (size_t)g * 8;
    r = make_ushort4((unsigned short)p[0], (unsigned short)p[2],
                     (unsigned short)p[4], (unsigned short)p[6]);
  } else {
    int4 c = ((const int4*)cidx)[g];
    r = make_ushort4((unsigned short)c.x, (unsigned short)c.y,
                     (unsigned short)c.z, (unsigned short)c.w);
  }
  out[g] = r;
}

extern "C" void kernel_launch(void* const* d_in, const int* in_sizes, int n_in,
                              void* d_out, int out_size, void* d_ws, size_t ws_size,
                              hipStream_t stream) {
  const float* x          = (const float*)d_in[0];
  const unsigned char* mg = (const unsigned char*)d_in[1];
  const int* cidx         = (const int*)d_in[2];
  float* out              = (float*)d_out;

  const size_t need = (size_t)N_LAYERS * NODES * sizeof(ushort4);  // 256 KB
  if (ws_size >= need) {
    ushort4* packed = (ushort4*)d_ws;
    hipLaunchKernelGGL(pack_idx, dim3((N_LAYERS * NODES) / 256), dim3(256), 0, stream,
                       cidx, packed);
    hipLaunchKernelGGL(spn_packed, dim3(BATCH / RPB), dim3(THREADS), 0, stream,
                       x, mg, packed, out);
  } else {
    hipLaunchKernelGGL(spn_raw, dim3(BATCH / RPB), dim3(THREADS), 0, stream,
                       x, mg, cidx, out);
  }
}